// Round 1
// baseline (550.549 us; speedup 1.0000x reference)
//
#include <hip/hip_runtime.h>
#include <hip/hip_bf16.h>
#include <math.h>

typedef __bf16 bf16;
typedef __bf16 bf16x4 __attribute__((ext_vector_type(4)));
typedef __bf16 bf16x8 __attribute__((ext_vector_type(8)));
typedef float f32x4 __attribute__((ext_vector_type(4)));

#define GLB __attribute__((address_space(1)))
#define LDSAS __attribute__((address_space(3)))

// ---------------------------------------------------------------------------
// Dtype probe: flag=1 if d_in[0] is genuine fp32, 0 if packed bf16.
// ---------------------------------------------------------------------------
__global__ void probe_dtype(const unsigned int* __restrict__ X, int* __restrict__ flag) {
  int t = threadIdx.x;
  int cnt = 0;
  for (int i = t; i < 512; i += 64) {
    unsigned int e = (X[i] >> 7) & 0xFF;
    cnt += (e >= 110 && e <= 135) ? 1 : 0;
  }
#pragma unroll
  for (int off = 32; off > 0; off >>= 1) cnt += __shfl_down(cnt, off, 64);
  if (t == 0) flag[0] = (cnt < 256) ? 1 : 0;
}

// ---------------------------------------------------------------------------
// Fused prep (vectorized): transpose+cast Wq/Wk/Wv/Wo, cast X -> Xb.
// ---------------------------------------------------------------------------
__global__ void prep_weights(const void* __restrict__ Wq, const void* __restrict__ Wk,
                             const void* __restrict__ Wv, const void* __restrict__ Wo,
                             const void* __restrict__ X,
                             bf16* __restrict__ Wqkvt, bf16* __restrict__ Wot,
                             bf16* __restrict__ Xb, const int* __restrict__ flag) {
  const int f = flag[0];
  const int tx = threadIdx.x, ty = threadIdx.y;  // (8,32)
  __shared__ bf16 tile[32][34];
  int b = blockIdx.x;
  const void* W;
  bf16* out;
  int N, bx, by;
  if (b < 16384) {                       // Wq [4096][4096]
    W = Wq; out = Wqkvt; N = 4096; bx = b & 127; by = b >> 7;
  } else if (b < 20480) {                // Wk [4096][1024]
    b -= 16384; W = Wk; out = Wqkvt + (size_t)4096 * 4096; N = 1024; bx = b & 31; by = b >> 5;
  } else if (b < 24576) {                // Wv [4096][1024]
    b -= 20480; W = Wv; out = Wqkvt + (size_t)5120 * 4096; N = 1024; bx = b & 31; by = b >> 5;
  } else if (b < 40960) {                // Wo [4096][4096]
    b -= 24576; W = Wo; out = Wot; N = 4096; bx = b & 127; by = b >> 7;
  } else {                               // X cast [2048][4096], 8192 blocks
    b -= 40960;
    const int t = ty * 8 + tx;
    const size_t i = ((size_t)b * 256 + t) * 4;
    bf16x4 o;
    if (f) {
      const float4 v = *(const float4*)((const float*)X + i);
      o[0] = (bf16)v.x; o[1] = (bf16)v.y; o[2] = (bf16)v.z; o[3] = (bf16)v.w;
    } else {
      o = *(const bf16x4*)((const bf16*)X + i);
    }
    *(bf16x4*)&Xb[i] = o;
    return;
  }
  const int n0 = bx * 32, k0 = by * 32;
  if (f) {
    const float4 v = *(const float4*)((const float*)W + (size_t)(k0 + ty) * N + n0 + 4 * tx);
    tile[ty][4 * tx + 0] = (bf16)v.x;
    tile[ty][4 * tx + 1] = (bf16)v.y;
    tile[ty][4 * tx + 2] = (bf16)v.z;
    tile[ty][4 * tx + 3] = (bf16)v.w;
  } else {
    const bf16x4 v = *(const bf16x4*)((const bf16*)W + (size_t)(k0 + ty) * N + n0 + 4 * tx);
#pragma unroll
    for (int u = 0; u < 4; ++u) tile[ty][4 * tx + u] = v[u];
  }
  __syncthreads();
  bf16x4 o;
#pragma unroll
  for (int u = 0; u < 4; ++u) o[u] = tile[4 * tx + u][ty];
  *(bf16x4*)&out[(size_t)(n0 + ty) * 4096 + k0 + 4 * tx] = o;
}

// ---------------------------------------------------------------------------
// 8-phase 256-row GEMM (HK-style schedule in plain HIP).
//   BM=256, BK=64, 8 waves (2M x 4N), templated BN (256 or 128).
//   LDS: double-buffered A[256x64] + B[BN x 64], XOR-swizzled (st-16x32-like):
//     phys_chunk = logical_chunk ^ (row&7)  (chunk = 16B)
//     staging pre-swizzles the per-lane GLOBAL source, LDS dest stays linear
//     (global_load_lds is wave-uniform base + lane*16 -> rule 21).
//   Main loop per K-tile:
//     stage(kt+1) -> s_waitcnt vmcnt(LPT) [counted, never 0] -> s_barrier
//     4 phases: {ds_read frags; s_barrier; lgkmcnt(0); sched_barrier;
//                setprio(1); MFMA cluster; setprio(0); s_barrier}
//   Correctness: each wave's phase ds_reads complete (lgkmcnt(0)) BEFORE its
//   phase-end barrier, so the next tile's global_load_lds (issued only after
//   that barrier) can never overwrite LDS under a pending read. The boundary
//   vmcnt(LPT)+barrier proves the current tile's staging is globally done
//   while keeping the next tile's LPT loads in flight across the barrier.
// ---------------------------------------------------------------------------
template <int BN>
__global__ __launch_bounds__(512, 2) void gemm8(
    const bf16* __restrict__ A, const bf16* __restrict__ Bt,
    void* __restrict__ C, const int* __restrict__ flagp,
    int M, int N, int K) {
  constexpr int NF  = BN / 64;   // per-wave n-fragments (wave covers BN/4 cols)
  constexpr int NB  = BN / 64;   // B staging insts per thread per tile
  constexpr int LPT = 4 + NB;    // global_load_lds per thread per tile
  __shared__ __attribute__((aligned(16))) bf16 As[2][256 * 64];
  __shared__ __attribute__((aligned(16))) bf16 Bs[2][BN * 64];

  const int t = threadIdx.x;
  const int w = t >> 6, lane = t & 63;
  const int n16 = lane & 15, quad = lane >> 4;
  const int wr = w >> 2, wc = w & 3;
  const int m0 = blockIdx.y * 256, n0 = blockIdx.x * BN;
  (void)M;

  f32x4 acc[8][NF] = {};

  // staging geometry: inst i covers rows i*64..i*64+63; thread t -> row i*64+(t>>3),
  // 16B phys chunk (t&7); source chunk pre-swizzled so reads can un-swizzle.
  const int srow = t >> 3;
  const int scol = ((t & 7) ^ (srow & 7)) * 8;
  const bf16* pa[4];
  const bf16* pb[NB];
#pragma unroll
  for (int i = 0; i < 4; ++i) pa[i] = A + (size_t)(m0 + i * 64 + srow) * K + scol;
#pragma unroll
  for (int i = 0; i < NB; ++i) pb[i] = Bt + (size_t)(n0 + i * 64 + srow) * K + scol;

  auto stage = [&](int kt, int buf) {
    const int koff = kt * 64;
#pragma unroll
    for (int i = 0; i < 4; ++i)
      __builtin_amdgcn_global_load_lds((const GLB void*)(pa[i] + koff),
                                       (LDSAS void*)(&As[buf][i * 4096 + t * 8]),
                                       16, 0, 0);
#pragma unroll
    for (int i = 0; i < NB; ++i)
      __builtin_amdgcn_global_load_lds((const GLB void*)(pb[i] + koff),
                                       (LDSAS void*)(&Bs[buf][i * 4096 + t * 8]),
                                       16, 0, 0);
  };

  const int nt = K >> 6;
  const int rdk = n16 & 7;

  stage(0, 0);
  for (int kt = 0; kt < nt; ++kt) {
    const int cur = kt & 1;
    if (kt + 1 < nt) {
      stage(kt + 1, cur ^ 1);
      if constexpr (LPT == 8)
        asm volatile("s_waitcnt vmcnt(8)" ::: "memory");
      else
        asm volatile("s_waitcnt vmcnt(6)" ::: "memory");
    } else {
      asm volatile("s_waitcnt vmcnt(0)" ::: "memory");
    }
    __builtin_amdgcn_s_barrier();
    const bf16* Asb = &As[cur][0];
    const bf16* Bsb = &Bs[cur][0];
#pragma unroll
    for (int ph = 0; ph < 4; ++ph) {
      const int mh = ph >> 1, ks = ph & 1;
      bf16x8 af[4], bfv[NF];
#pragma unroll
      for (int mf = 0; mf < 4; ++mf)
        af[mf] = *(const bf16x8*)&Asb[(wr * 128 + mh * 64 + mf * 16 + n16) * 64 +
                                      (((ks * 4 + quad) ^ rdk) * 8)];
#pragma unroll
      for (int nf = 0; nf < NF; ++nf)
        bfv[nf] = *(const bf16x8*)&Bsb[(wc * (BN / 4) + nf * 16 + n16) * 64 +
                                       (((ks * 4 + quad) ^ rdk) * 8)];
      __builtin_amdgcn_s_barrier();
      asm volatile("s_waitcnt lgkmcnt(0)" ::: "memory");
      __builtin_amdgcn_sched_barrier(0);
      __builtin_amdgcn_s_setprio(1);
#pragma unroll
      for (int mf = 0; mf < 4; ++mf)
#pragma unroll
        for (int nf = 0; nf < NF; ++nf)
          acc[mh * 4 + mf][nf] = __builtin_amdgcn_mfma_f32_16x16x32_bf16(
              af[mf], bfv[nf], acc[mh * 4 + mf][nf], 0, 0, 0);
      __builtin_amdgcn_s_setprio(0);
      __builtin_amdgcn_s_barrier();
    }
  }

  const bool f32out = (flagp != nullptr) && (flagp[0] != 0);
  if (f32out) {
    float* Cf = (float*)C;
#pragma unroll
    for (int mi = 0; mi < 8; ++mi)
#pragma unroll
      for (int nf = 0; nf < NF; ++nf) {
        const int r0 = m0 + wr * 128 + (mi >> 2) * 64 + (mi & 3) * 16 + quad * 4;
        const int c = n0 + wc * (BN / 4) + nf * 16 + n16;
#pragma unroll
        for (int r = 0; r < 4; ++r) Cf[(size_t)(r0 + r) * N + c] = acc[mi][nf][r];
      }
  } else {
    bf16* Cb = (bf16*)C;
#pragma unroll
    for (int mi = 0; mi < 8; ++mi)
#pragma unroll
      for (int nf = 0; nf < NF; ++nf) {
        const int r0 = m0 + wr * 128 + (mi >> 2) * 64 + (mi & 3) * 16 + quad * 4;
        const int c = n0 + wc * (BN / 4) + nf * 16 + n16;
#pragma unroll
        for (int r = 0; r < 4; ++r) Cb[(size_t)(r0 + r) * N + c] = (bf16)acc[mi][nf][r];
      }
  }
}

// ---------------------------------------------------------------------------
// Fused RoPE (Q+K, cols<5120) + V transpose (cols>=5120 -> Vt).
// ---------------------------------------------------------------------------
__global__ void rope_vt(bf16* __restrict__ QKV, const int* __restrict__ pos,
                        bf16* __restrict__ Vt) {
  const int t = threadIdx.x;
  int b = blockIdx.x;
  if (b < 20480) {  // RoPE on heads 0..39
    const int idx = b * 256 + t;
    const int i = idx & 63;
    const int hh = (idx >> 6) % 40;
    const int s = idx / (64 * 40);
    bf16* px = QKV + (size_t)s * 6144 + hh * 128 + i;
    const float x1 = (float)px[0], x2 = (float)px[64];
    const float p = (float)pos[s];
    const float inv = exp2f((float)i * -0.2076205088f);  // 10000^(-i/64)
    float sn, cs;
    sincosf(p * inv, &sn, &cs);
    px[0] = (bf16)(x1 * cs - x2 * sn);
    px[64] = (bf16)(x2 * cs + x1 * sn);
  } else {          // V transpose: [2048 s][1024 v] (stride 6144) -> Vt[v][s]
    b -= 20480;
    __shared__ bf16 tile[32][34];
    const int tx = t & 31, ty = t >> 5;
    const int v0 = (b & 31) * 32, s0 = (b >> 5) * 32;
#pragma unroll
    for (int j = 0; j < 4; ++j)
      tile[ty + j * 8][tx] = QKV[(size_t)(s0 + ty + j * 8) * 6144 + 5120 + v0 + tx];
    __syncthreads();
#pragma unroll
    for (int j = 0; j < 4; ++j)
      Vt[(size_t)(v0 + ty + j * 8) * 2048 + s0 + tx] = tile[tx][ty + j * 8];
  }
}

// ---------------------------------------------------------------------------
// Flash attention v5 (unchanged this round).
// ---------------------------------------------------------------------------
__global__ __launch_bounds__(256) void flash_attn(
    const bf16* __restrict__ QKV, const bf16* __restrict__ Vt_g,
    bf16* __restrict__ O) {
  __shared__ bf16 Ks[2][64 * 128];
  __shared__ bf16 Vs[2][128 * 64];
  __shared__ bf16 Ps[64 * 72];
  const int pairp = blockIdx.x;
  const int h = blockIdx.y, hkv = h >> 2;
  const int t = threadIdx.x, w = t >> 6, lane = t & 63;
  const int n16 = lane & 15, quad = lane >> 4;
  const bf16* Qp = QKV + h * 128;
  const bf16* Kp = QKV + 4096 + hkv * 128;
  const bf16* Vp = Vt_g + (size_t)hkv * 128 * 2048;

  const int krow = t >> 4, kg = t & 15;
  const int vd = t >> 3, vg = t & 7;

  for (int pass = 0; pass < 2; ++pass) {
    const int qt = (pass == 0) ? pairp : 31 - pairp;
    bf16x8 qa[4];
    {
      const bf16* qrow = Qp + (size_t)(qt * 64 + w * 16 + n16) * 6144 + quad * 8;
#pragma unroll
      for (int kf = 0; kf < 4; ++kf) qa[kf] = *(const bf16x8*)(qrow + kf * 32);
    }
    f32x4 o[8] = {};
    float l_[4] = {0.f, 0.f, 0.f, 0.f};

    __syncthreads();

    auto stage = [&](int kt, int buf) {
#pragma unroll
      for (int j = 0; j < 4; ++j) {
        const int row = j * 16 + krow;
        const int g = kg ^ (row & 7);
        __builtin_amdgcn_global_load_lds(
            (const GLB void*)(Kp + (size_t)(kt * 64 + row) * 6144 + g * 8),
            (LDSAS void*)(&Ks[buf][j * 2048 + t * 8]), 16, 0, 0);
      }
#pragma unroll
      for (int j = 0; j < 4; ++j) {
        const int d = j * 32 + vd;
        const int g = vg ^ (d & 7);
        __builtin_amdgcn_global_load_lds(
            (const GLB void*)(Vp + (size_t)d * 2048 + kt * 64 + g * 8),
            (LDSAS void*)(&Vs[buf][j * 2048 + t * 8]), 16, 0, 0);
      }
    };

    stage(0, 0);
    for (int kt = 0; kt <= qt; ++kt) {
      const int cur = kt & 1;
      __syncthreads();
      if (kt < qt) stage(kt + 1, cur ^ 1);

      float p[4][4];
      const bool diag = (kt == qt);
      const int s7 = n16 & 7;
#pragma unroll
      for (int ns = 0; ns < 4; ++ns) {
        f32x4 c = {};
#pragma unroll
        for (int kf = 0; kf < 4; ++kf)
          c = __builtin_amdgcn_mfma_f32_16x16x32_bf16(
              qa[kf],
              *(const bf16x8*)&Ks[cur][(ns * 16 + n16) * 128 +
                                       (((kf * 4 + quad) ^ s7) * 8)],
              c, 0, 0, 0);
        if (diag) {
          const int kvi = ns * 16 + n16;
          const int ql = w * 16 + quad * 4;
#pragma unroll
          for (int r = 0; r < 4; ++r)
            p[ns][r] = (kvi > ql + r)
                           ? 0.f
                           : __expf(fminf(c[r] * 0.08838834764831845f, 60.f));
        } else {
#pragma unroll
          for (int r = 0; r < 4; ++r)
            p[ns][r] = __expf(fminf(c[r] * 0.08838834764831845f, 60.f));
        }
      }
#pragma unroll
      for (int r = 0; r < 4; ++r)
        l_[r] += (p[0][r] + p[1][r]) + (p[2][r] + p[3][r]);
#pragma unroll
      for (int ns = 0; ns < 4; ++ns)
#pragma unroll
        for (int r = 0; r < 4; ++r)
          Ps[(w * 16 + quad * 4 + r) * 72 + ns * 16 + n16] = (bf16)p[ns][r];
      const bf16x8 a0 = *(const bf16x8*)&Ps[(w * 16 + n16) * 72 + quad * 8];
      const bf16x8 a1 = *(const bf16x8*)&Ps[(w * 16 + n16) * 72 + 32 + quad * 8];
#pragma unroll
      for (int dt = 0; dt < 8; ++dt) {
        const int d = dt * 16 + n16;
        const bf16x8 b0 = *(const bf16x8*)&Vs[cur][d * 64 + ((quad ^ s7) * 8)];
        o[dt] = __builtin_amdgcn_mfma_f32_16x16x32_bf16(a0, b0, o[dt], 0, 0, 0);
        const bf16x8 b1 = *(const bf16x8*)&Vs[cur][d * 64 + (((4 + quad) ^ s7) * 8)];
        o[dt] = __builtin_amdgcn_mfma_f32_16x16x32_bf16(a1, b1, o[dt], 0, 0, 0);
      }
    }
#pragma unroll
    for (int r = 0; r < 4; ++r) {
#pragma unroll
      for (int off = 1; off < 16; off <<= 1) l_[r] += __shfl_xor(l_[r], off, 64);
    }
    float linv[4];
#pragma unroll
    for (int r = 0; r < 4; ++r) linv[r] = 1.f / l_[r];
#pragma unroll
    for (int dt = 0; dt < 8; ++dt)
#pragma unroll
      for (int r = 0; r < 4; ++r) {
        const int qi = qt * 64 + w * 16 + quad * 4 + r;
        O[(size_t)qi * 4096 + h * 128 + dt * 16 + n16] = (bf16)(o[dt][r] * linv[r]);
      }
  }
}

// ---------------------------------------------------------------------------
extern "C" void kernel_launch(void* const* d_in, const int* in_sizes, int n_in,
                              void* d_out, int out_size, void* d_ws, size_t ws_size,
                              hipStream_t stream) {
  (void)in_sizes; (void)n_in; (void)out_size; (void)ws_size;
  const void* X = d_in[0];
  const int* pos = (const int*)d_in[1];
  const void* Wq = d_in[2];
  const void* Wk = d_in[3];
  const void* Wv = d_in[4];
  const void* Wo = d_in[5];

  char* ws = (char*)d_ws;
  const size_t MB = 1ull << 20;
  int* flag   = (int*)(ws + 0);
  bf16* Xb    = (bf16*)(ws + 1 * MB);    // 16 MiB (aliased by attn later)
  bf16* attn  = (bf16*)(ws + 1 * MB);    // alias: Xb dead after QKV GEMM
  bf16* Wqkvt = (bf16*)(ws + 17 * MB);   // [6144][4096] = 48 MiB
  bf16* Wot   = (bf16*)(ws + 65 * MB);   // 32 MiB
  bf16* QKV   = (bf16*)(ws + 97 * MB);   // [2048][6144] = 24 MiB
  bf16* Vt_g  = (bf16*)(ws + 121 * MB);  // [1024][2048] = 4 MiB -> 125 MiB

  probe_dtype<<<1, 64, 0, stream>>>((const unsigned int*)X, flag);

  prep_weights<<<49152, dim3(8, 32), 0, stream>>>(Wq, Wk, Wv, Wo, X,
                                                  Wqkvt, Wot, Xb, flag);

  // fused QKV projection: [2048][4096] @ [4096][6144]^T-stored -> [2048][6144]
  // BM=256 x BN=256 -> grid 24x8 = 192 blocks
  gemm8<256><<<dim3(24, 8), 512, 0, stream>>>(Xb, Wqkvt, QKV, nullptr, 2048, 6144, 4096);

  rope_vt<<<22528, 256, 0, stream>>>(QKV, pos, Vt_g);  // RoPE(Q,K) + V^T

  flash_attn<<<dim3(16, 32), 256, 0, stream>>>(QKV, Vt_g, attn);

  // output projection: BM=256 x BN=128 -> grid 32x8 = 256 blocks (1 per CU)
  gemm8<128><<<dim3(32, 8), 512, 0, stream>>>(attn, Wot, d_out, flag, 2048, 4096, 4096);
}

// Round 2
// 489.421 us; speedup vs baseline: 1.1249x; 1.1249x over previous
//
#include <hip/hip_runtime.h>
#include <hip/hip_bf16.h>
#include <math.h>

typedef __bf16 bf16;
typedef __bf16 bf16x4 __attribute__((ext_vector_type(4)));
typedef __bf16 bf16x8 __attribute__((ext_vector_type(8)));
typedef float f32x4 __attribute__((ext_vector_type(4)));

#define GLB __attribute__((address_space(1)))
#define LDSAS __attribute__((address_space(3)))

// ---------------------------------------------------------------------------
// Dtype probe: flag=1 if d_in[0] is genuine fp32, 0 if packed bf16.
// ---------------------------------------------------------------------------
__global__ void probe_dtype(const unsigned int* __restrict__ X, int* __restrict__ flag) {
  int t = threadIdx.x;
  int cnt = 0;
  for (int i = t; i < 512; i += 64) {
    unsigned int e = (X[i] >> 7) & 0xFF;
    cnt += (e >= 110 && e <= 135) ? 1 : 0;
  }
#pragma unroll
  for (int off = 32; off > 0; off >>= 1) cnt += __shfl_down(cnt, off, 64);
  if (t == 0) flag[0] = (cnt < 256) ? 1 : 0;
}

// ---------------------------------------------------------------------------
// Prep v2: transpose+cast with 16B-coalesced writes.
//   64x64 tile, 256 flat threads. Reads float4/bf16x4 (16B/8B per lane,
//   coalesced). LDS holds the tile TRANSPOSED (tileT[n][k], 72-elem rows =
//   144B, 16B-aligned) so the write side is one bf16x8 = 16B/lane, 128B per
//   output row per 8 lanes (vs 64B segments in v1). Scatter-in is scalar
//   ds_write_b16 with a 16B-chunk XOR swizzle keyed on n>>3 (wave-uniform on
//   the read side, per-lane on the write side) keeping conflicts <=4-way.
//   X-cast branch unchanged (flat).
// ---------------------------------------------------------------------------
__global__ void prep_weights(const void* __restrict__ Wq, const void* __restrict__ Wk,
                             const void* __restrict__ Wv, const void* __restrict__ Wo,
                             const void* __restrict__ X,
                             bf16* __restrict__ Wqkvt, bf16* __restrict__ Wot,
                             bf16* __restrict__ Xb, const int* __restrict__ flag) {
  const int f = flag[0];
  const int t = threadIdx.x;  // 256 flat
  int b = blockIdx.x;
  __shared__ __attribute__((aligned(16))) bf16 tileT[64][72];
  const void* W;
  bf16* out;
  int N, bx, by;
  if (b < 4096) {                        // Wq [4096][4096]
    W = Wq; out = Wqkvt; N = 4096; bx = b & 63; by = b >> 6;
  } else if (b < 5120) {                 // Wk [4096][1024]
    b -= 4096; W = Wk; out = Wqkvt + (size_t)4096 * 4096; N = 1024; bx = b & 15; by = b >> 4;
  } else if (b < 6144) {                 // Wv [4096][1024]
    b -= 5120; W = Wv; out = Wqkvt + (size_t)5120 * 4096; N = 1024; bx = b & 15; by = b >> 4;
  } else if (b < 10240) {                // Wo [4096][4096]
    b -= 6144; W = Wo; out = Wot; N = 4096; bx = b & 63; by = b >> 6;
  } else {                               // X cast [2048][4096], 8192 blocks
    b -= 10240;
    const size_t i = ((size_t)b * 256 + t) * 4;
    bf16x4 o;
    if (f) {
      const float4 v = *(const float4*)((const float*)X + i);
      o[0] = (bf16)v.x; o[1] = (bf16)v.y; o[2] = (bf16)v.z; o[3] = (bf16)v.w;
    } else {
      o = *(const bf16x4*)((const bf16*)X + i);
    }
    *(bf16x4*)&Xb[i] = o;
    return;
  }
  const int n0 = bx * 64, k0 = by * 64;

  // ---- read in: 4 passes x 16 rows; lane covers 4 consecutive n
  const int rr = t >> 4, cc = (t & 15) * 4;
  const int s_in = (t & 15) >> 1;  // = ((cc+u)>>3)&7 for u<4 (no carry past bit 3)
#pragma unroll
  for (int p = 0; p < 4; ++p) {
    const int r = p * 16 + rr;
    bf16 vals[4];
    if (f) {
      const float4 v = *(const float4*)((const float*)W + (size_t)(k0 + r) * N + n0 + cc);
      vals[0] = (bf16)v.x; vals[1] = (bf16)v.y; vals[2] = (bf16)v.z; vals[3] = (bf16)v.w;
    } else {
      const bf16x4 v = *(const bf16x4*)((const bf16*)W + (size_t)(k0 + r) * N + n0 + cc);
#pragma unroll
      for (int u = 0; u < 4; ++u) vals[u] = v[u];
    }
    const int idx = (((r >> 3) ^ s_in) << 3) + (r & 7);  // swizzled k-position
#pragma unroll
    for (int u = 0; u < 4; ++u) tileT[cc + u][idx] = vals[u];
  }
  __syncthreads();

  // ---- write out: 2 passes x 32 rows; one bf16x8 (16B) per lane per pass
  const int nn = t >> 3, c8 = t & 7;
#pragma unroll
  for (int p = 0; p < 2; ++p) {
    const int n = p * 32 + nn;
    const int s = (n >> 3) & 7;
    const bf16x8 v = *(const bf16x8*)&tileT[n][(c8 ^ s) * 8];
    *(bf16x8*)&out[(size_t)(n0 + n) * 4096 + k0 + c8 * 8] = v;
  }
}

// ---------------------------------------------------------------------------
// m97-style bf16 GEMM with XOR-swizzled LDS (conflict-free, verified 0).
// REVERTED to the harness-verified round-0 version (128/85 us): the 8-phase
// 256^2 port regressed (1 block/CU -> every barrier fully exposed; boundary
// vmcnt burst instead of per-phase spread). Keep the 2.5-blocks/CU structure.
// ---------------------------------------------------------------------------
__global__ __launch_bounds__(256, 2) void gemm_bt(
    const bf16* __restrict__ A, const bf16* __restrict__ Bt,
    void* __restrict__ C, const int* __restrict__ flagp, int M, int N, int K) {
  __shared__ bf16 As[128 * 32];
  __shared__ bf16 Bs[128 * 32];
  const int t = threadIdx.x;
  const int m0 = blockIdx.y * 128, n0 = blockIdx.x * 128;
  const int lane = t & 63, n16 = lane & 15, quad = lane >> 4;
  const int w = t >> 6, wrow = w >> 1, wcol = w & 1;

  f32x4 acc[4][4] = {};
  const int colA = (((t & 3) ^ ((t >> 3) & 3))) * 8;  // swizzled k-chunk
  const int rA = t >> 2;
  const int sw = (n16 >> 1) & 3;                       // read-side swizzle
  const int rdoff = ((quad ^ sw) * 8);

  for (int k0 = 0; k0 < K; k0 += 32) {
#pragma unroll
    for (int i = 0; i < 2; ++i) {
      const int elem = i * 2048 + t * 8;
      const int row = i * 64 + rA;
      __builtin_amdgcn_global_load_lds(
          (const GLB void*)(A + (size_t)(m0 + row) * K + k0 + colA),
          (LDSAS void*)(&As[elem]), 16, 0, 0);
      __builtin_amdgcn_global_load_lds(
          (const GLB void*)(Bt + (size_t)(n0 + row) * K + k0 + colA),
          (LDSAS void*)(&Bs[elem]), 16, 0, 0);
    }
    __syncthreads();
    bf16x8 af[4], bfr[4];
#pragma unroll
    for (int i = 0; i < 4; ++i) {
      af[i] = *(const bf16x8*)&As[(wrow * 64 + i * 16 + n16) * 32 + rdoff];
      bfr[i] = *(const bf16x8*)&Bs[(wcol * 64 + i * 16 + n16) * 32 + rdoff];
    }
#pragma unroll
    for (int mi = 0; mi < 4; ++mi)
#pragma unroll
      for (int ni = 0; ni < 4; ++ni)
        acc[mi][ni] = __builtin_amdgcn_mfma_f32_16x16x32_bf16(
            af[mi], bfr[ni], acc[mi][ni], 0, 0, 0);
    __syncthreads();
  }
  const bool f32out = (flagp != nullptr) && (flagp[0] != 0);
  if (f32out) {
    float* Cf = (float*)C;
#pragma unroll
    for (int mi = 0; mi < 4; ++mi)
#pragma unroll
      for (int ni = 0; ni < 4; ++ni) {
        const int r0 = m0 + wrow * 64 + mi * 16 + quad * 4;
        const int c = n0 + wcol * 64 + ni * 16 + n16;
#pragma unroll
        for (int r = 0; r < 4; ++r) Cf[(size_t)(r0 + r) * N + c] = acc[mi][ni][r];
      }
  } else {
    bf16* Cb = (bf16*)C;
#pragma unroll
    for (int mi = 0; mi < 4; ++mi)
#pragma unroll
      for (int ni = 0; ni < 4; ++ni) {
        const int r0 = m0 + wrow * 64 + mi * 16 + quad * 4;
        const int c = n0 + wcol * 64 + ni * 16 + n16;
#pragma unroll
        for (int r = 0; r < 4; ++r) Cb[(size_t)(r0 + r) * N + c] = (bf16)acc[mi][ni][r];
      }
  }
}

// ---------------------------------------------------------------------------
// Fused RoPE (Q+K, cols<5120) + V transpose (cols>=5120 -> Vt).
// ---------------------------------------------------------------------------
__global__ void rope_vt(bf16* __restrict__ QKV, const int* __restrict__ pos,
                        bf16* __restrict__ Vt) {
  const int t = threadIdx.x;
  int b = blockIdx.x;
  if (b < 20480) {  // RoPE on heads 0..39
    const int idx = b * 256 + t;
    const int i = idx & 63;
    const int hh = (idx >> 6) % 40;
    const int s = idx / (64 * 40);
    bf16* px = QKV + (size_t)s * 6144 + hh * 128 + i;
    const float x1 = (float)px[0], x2 = (float)px[64];
    const float p = (float)pos[s];
    const float inv = exp2f((float)i * -0.2076205088f);  // 10000^(-i/64)
    float sn, cs;
    sincosf(p * inv, &sn, &cs);
    px[0] = (bf16)(x1 * cs - x2 * sn);
    px[64] = (bf16)(x2 * cs + x1 * sn);
  } else {          // V transpose: [2048 s][1024 v] (stride 6144) -> Vt[v][s]
    b -= 20480;
    __shared__ bf16 tile[32][34];
    const int tx = t & 31, ty = t >> 5;
    const int v0 = (b & 31) * 32, s0 = (b >> 5) * 32;
#pragma unroll
    for (int j = 0; j < 4; ++j)
      tile[ty + j * 8][tx] = QKV[(size_t)(s0 + ty + j * 8) * 6144 + 5120 + v0 + tx];
    __syncthreads();
#pragma unroll
    for (int j = 0; j < 4; ++j)
      Vt[(size_t)(v0 + ty + j * 8) * 2048 + s0 + tx] = tile[tx][ty + j * 8];
  }
}

// ---------------------------------------------------------------------------
// Flash attention v5 (unchanged).
// ---------------------------------------------------------------------------
__global__ __launch_bounds__(256) void flash_attn(
    const bf16* __restrict__ QKV, const bf16* __restrict__ Vt_g,
    bf16* __restrict__ O) {
  __shared__ bf16 Ks[2][64 * 128];
  __shared__ bf16 Vs[2][128 * 64];
  __shared__ bf16 Ps[64 * 72];
  const int pairp = blockIdx.x;
  const int h = blockIdx.y, hkv = h >> 2;
  const int t = threadIdx.x, w = t >> 6, lane = t & 63;
  const int n16 = lane & 15, quad = lane >> 4;
  const bf16* Qp = QKV + h * 128;
  const bf16* Kp = QKV + 4096 + hkv * 128;
  const bf16* Vp = Vt_g + (size_t)hkv * 128 * 2048;

  const int krow = t >> 4, kg = t & 15;
  const int vd = t >> 3, vg = t & 7;

  for (int pass = 0; pass < 2; ++pass) {
    const int qt = (pass == 0) ? pairp : 31 - pairp;
    bf16x8 qa[4];
    {
      const bf16* qrow = Qp + (size_t)(qt * 64 + w * 16 + n16) * 6144 + quad * 8;
#pragma unroll
      for (int kf = 0; kf < 4; ++kf) qa[kf] = *(const bf16x8*)(qrow + kf * 32);
    }
    f32x4 o[8] = {};
    float l_[4] = {0.f, 0.f, 0.f, 0.f};

    __syncthreads();

    auto stage = [&](int kt, int buf) {
#pragma unroll
      for (int j = 0; j < 4; ++j) {
        const int row = j * 16 + krow;
        const int g = kg ^ (row & 7);
        __builtin_amdgcn_global_load_lds(
            (const GLB void*)(Kp + (size_t)(kt * 64 + row) * 6144 + g * 8),
            (LDSAS void*)(&Ks[buf][j * 2048 + t * 8]), 16, 0, 0);
      }
#pragma unroll
      for (int j = 0; j < 4; ++j) {
        const int d = j * 32 + vd;
        const int g = vg ^ (d & 7);
        __builtin_amdgcn_global_load_lds(
            (const GLB void*)(Vp + (size_t)d * 2048 + kt * 64 + g * 8),
            (LDSAS void*)(&Vs[buf][j * 2048 + t * 8]), 16, 0, 0);
      }
    };

    stage(0, 0);
    for (int kt = 0; kt <= qt; ++kt) {
      const int cur = kt & 1;
      __syncthreads();
      if (kt < qt) stage(kt + 1, cur ^ 1);

      float p[4][4];
      const bool diag = (kt == qt);
      const int s7 = n16 & 7;
#pragma unroll
      for (int ns = 0; ns < 4; ++ns) {
        f32x4 c = {};
#pragma unroll
        for (int kf = 0; kf < 4; ++kf)
          c = __builtin_amdgcn_mfma_f32_16x16x32_bf16(
              qa[kf],
              *(const bf16x8*)&Ks[cur][(ns * 16 + n16) * 128 +
                                       (((kf * 4 + quad) ^ s7) * 8)],
              c, 0, 0, 0);
        if (diag) {
          const int kvi = ns * 16 + n16;
          const int ql = w * 16 + quad * 4;
#pragma unroll
          for (int r = 0; r < 4; ++r)
            p[ns][r] = (kvi > ql + r)
                           ? 0.f
                           : __expf(fminf(c[r] * 0.08838834764831845f, 60.f));
        } else {
#pragma unroll
          for (int r = 0; r < 4; ++r)
            p[ns][r] = __expf(fminf(c[r] * 0.08838834764831845f, 60.f));
        }
      }
#pragma unroll
      for (int r = 0; r < 4; ++r)
        l_[r] += (p[0][r] + p[1][r]) + (p[2][r] + p[3][r]);
#pragma unroll
      for (int ns = 0; ns < 4; ++ns)
#pragma unroll
        for (int r = 0; r < 4; ++r)
          Ps[(w * 16 + quad * 4 + r) * 72 + ns * 16 + n16] = (bf16)p[ns][r];
      const bf16x8 a0 = *(const bf16x8*)&Ps[(w * 16 + n16) * 72 + quad * 8];
      const bf16x8 a1 = *(const bf16x8*)&Ps[(w * 16 + n16) * 72 + 32 + quad * 8];
#pragma unroll
      for (int dt = 0; dt < 8; ++dt) {
        const int d = dt * 16 + n16;
        const bf16x8 b0 = *(const bf16x8*)&Vs[cur][d * 64 + ((quad ^ s7) * 8)];
        o[dt] = __builtin_amdgcn_mfma_f32_16x16x32_bf16(a0, b0, o[dt], 0, 0, 0);
        const bf16x8 b1 = *(const bf16x8*)&Vs[cur][d * 64 + (((4 + quad) ^ s7) * 8)];
        o[dt] = __builtin_amdgcn_mfma_f32_16x16x32_bf16(a1, b1, o[dt], 0, 0, 0);
      }
    }
#pragma unroll
    for (int r = 0; r < 4; ++r) {
#pragma unroll
      for (int off = 1; off < 16; off <<= 1) l_[r] += __shfl_xor(l_[r], off, 64);
    }
    float linv[4];
#pragma unroll
    for (int r = 0; r < 4; ++r) linv[r] = 1.f / l_[r];
#pragma unroll
    for (int dt = 0; dt < 8; ++dt)
#pragma unroll
      for (int r = 0; r < 4; ++r) {
        const int qi = qt * 64 + w * 16 + quad * 4 + r;
        O[(size_t)qi * 4096 + h * 128 + dt * 16 + n16] = (bf16)(o[dt][r] * linv[r]);
      }
  }
}

// ---------------------------------------------------------------------------
extern "C" void kernel_launch(void* const* d_in, const int* in_sizes, int n_in,
                              void* d_out, int out_size, void* d_ws, size_t ws_size,
                              hipStream_t stream) {
  (void)in_sizes; (void)n_in; (void)out_size; (void)ws_size;
  const void* X = d_in[0];
  const int* pos = (const int*)d_in[1];
  const void* Wq = d_in[2];
  const void* Wk = d_in[3];
  const void* Wv = d_in[4];
  const void* Wo = d_in[5];

  char* ws = (char*)d_ws;
  const size_t MB = 1ull << 20;
  int* flag   = (int*)(ws + 0);
  bf16* Xb    = (bf16*)(ws + 1 * MB);    // 16 MiB (aliased by attn later)
  bf16* attn  = (bf16*)(ws + 1 * MB);    // alias: Xb dead after QKV GEMM
  bf16* Wqkvt = (bf16*)(ws + 17 * MB);   // [6144][4096] = 48 MiB
  bf16* Wot   = (bf16*)(ws + 65 * MB);   // 32 MiB
  bf16* QKV   = (bf16*)(ws + 97 * MB);   // [2048][6144] = 24 MiB
  bf16* Vt_g  = (bf16*)(ws + 121 * MB);  // [1024][2048] = 4 MiB -> 125 MiB

  probe_dtype<<<1, 64, 0, stream>>>((const unsigned int*)X, flag);

  // 10240 transpose blocks (64x64 tiles) + 8192 X-cast blocks
  prep_weights<<<18432, 256, 0, stream>>>(Wq, Wk, Wv, Wo, X, Wqkvt, Wot, Xb, flag);

  // fused QKV projection: [2048][4096] @ [4096][6144]^T-stored -> [2048][6144]
  gemm_bt<<<dim3(48, 16), 256, 0, stream>>>(Xb, Wqkvt, QKV, nullptr, 2048, 6144, 4096);

  rope_vt<<<22528, 256, 0, stream>>>(QKV, pos, Vt_g);  // RoPE(Q,K) + V^T

  flash_attn<<<dim3(16, 32), 256, 0, stream>>>(QKV, Vt_g, attn);

  gemm_bt<<<dim3(32, 16), 256, 0, stream>>>(attn, Wot, d_out, flag, 2048, 4096, 4096);
}